// Round 3
// baseline (911.245 us; speedup 1.0000x reference)
//
#include <hip/hip_runtime.h>

// Problem constants (from reference)
constexpr int N_NODES = 100000;
constexpr int N_EDGES = 1600000;
constexpr int D = 64;          // D_IN == D_OUT == 64

// Bucketing: 128 consecutive dst nodes per bucket.
constexpr int BSH    = 7;
constexpr int BNODES = 1 << BSH;                              // 128
constexpr int NBUCK  = (N_NODES + BNODES - 1) / BNODES;       // 782
constexpr int NPART  = 200;                                   // partition blocks
constexpr int EPB    = N_EDGES / NPART;                       // 8000 edges/block (exact)

// ---------------------------------------------------------------------------
// Workspace layout (bytes). Total must stay <= 40,280,064 (R2-verified size).
// ---------------------------------------------------------------------------
constexpr size_t OFF_BCNT    = 0;            // NBUCK ints
constexpr size_t OFF_CURSOR  = 4096;         // NBUCK ints
constexpr size_t OFF_BSTART  = 8192;         // NBUCK+1 ints
constexpr size_t OFF_ENTRIES = 16384;        // N_EDGES uint2 = 12.8 MB (ends 12,816,384)
constexpr size_t OFF_AGG     = 14680064;     // N_NODES*64 float = 25.6 MB
constexpr size_t WS_NEEDED   = OFF_AGG + (size_t)N_NODES * D * 4;   // 40,280,064

// ---------------------------------------------------------------------------
// K0: zero the bucket counters (ws is poisoned before every launch).
// ---------------------------------------------------------------------------
__global__ __launch_bounds__(256) void k_zero(int* __restrict__ bcnt) {
    int i = blockIdx.x * 256 + threadIdx.x;
    if (i < NBUCK) bcnt[i] = 0;
}

// ---------------------------------------------------------------------------
// K1: per-block LDS histogram of dst buckets -> global bucket counts.
// 200 blocks x 8000 edges; 156K global atomics instead of 1.6M.
// ---------------------------------------------------------------------------
__global__ __launch_bounds__(256) void k_bcount(const int* __restrict__ dst,
                                                int* __restrict__ bcnt) {
    __shared__ int l[NBUCK];
    const int tid  = threadIdx.x;
    const int base = blockIdx.x * EPB;
    for (int i = tid; i < NBUCK; i += 256) l[i] = 0;
    __syncthreads();
    for (int k = tid; k < EPB; k += 256)
        atomicAdd(&l[dst[base + k] >> BSH], 1);
    __syncthreads();
    for (int b = tid; b < NBUCK; b += 256)
        if (l[b]) atomicAdd(&bcnt[b], l[b]);
}

// ---------------------------------------------------------------------------
// K2: exclusive scan of the 782 bucket counts (one 1024-thread block).
// Writes bstart[0..NBUCK] and initializes the reservation cursors.
// ---------------------------------------------------------------------------
__global__ __launch_bounds__(1024) void k_scan(const int* __restrict__ bcnt,
                                               int* __restrict__ bstart,
                                               int* __restrict__ cursor) {
    __shared__ int s[1024];
    const int tid = threadIdx.x;
    const int v = (tid < NBUCK) ? bcnt[tid] : 0;
    s[tid] = v;
    __syncthreads();
    for (int off = 1; off < 1024; off <<= 1) {
        int u = (tid >= off) ? s[tid - off] : 0;
        __syncthreads();
        s[tid] += u;
        __syncthreads();
    }
    const int excl = s[tid] - v;
    if (tid <= NBUCK) bstart[tid] = excl;   // tid==NBUCK lands on N_EDGES
    if (tid < NBUCK)  cursor[tid] = excl;
}

// ---------------------------------------------------------------------------
// K3: partition edges into bucket-contiguous entries.
// Per-block LDS hist -> one atomic range reservation per (block,bucket) ->
// scatter {src | dst_local<<17, weight} with ~10-entry contiguous runs.
// ---------------------------------------------------------------------------
__global__ __launch_bounds__(256) void k_part(const int* __restrict__ src,
                                              const int* __restrict__ dst,
                                              const float* __restrict__ ew,
                                              int* __restrict__ cursor,
                                              uint2* __restrict__ entries) {
    __shared__ int l[NBUCK];
    const int tid  = threadIdx.x;
    const int base = blockIdx.x * EPB;
    for (int i = tid; i < NBUCK; i += 256) l[i] = 0;
    __syncthreads();
    for (int k = tid; k < EPB; k += 256)
        atomicAdd(&l[dst[base + k] >> BSH], 1);
    __syncthreads();
    for (int b = tid; b < NBUCK; b += 256) {
        const int c = l[b];
        l[b] = c ? atomicAdd(&cursor[b], c) : 0;
    }
    __syncthreads();
    for (int k = tid; k < EPB; k += 256) {
        const int e = base + k;
        const int d = dst[e];
        const int pos = atomicAdd(&l[d >> BSH], 1);
        entries[pos] = make_uint2((unsigned)src[e] | ((unsigned)(d & (BNODES - 1)) << 17),
                                  __float_as_uint(ew[e]));
    }
}

// ---------------------------------------------------------------------------
// K4: bucketed mean-aggregation. One block per bucket; 32 KB LDS f32
// accumulator (4 blocks/CU). Wave per edge, 4-deep unroll for gather ILP;
// lane j owns feature j -> conflict-free LDS atomics (2-way aliasing, free).
// ---------------------------------------------------------------------------
__global__ __launch_bounds__(256) void k_bagg(const float* __restrict__ feat,
                                              const int* __restrict__ bstart,
                                              const uint2* __restrict__ entries,
                                              float4* __restrict__ agg4) {
    __shared__ float acc[BNODES * D];   // 32 KB
    __shared__ int   degl[BNODES];
    const int tid = threadIdx.x;
    float4* acc4 = (float4*)acc;
    for (int i = tid; i < BNODES * D / 4; i += 256)
        acc4[i] = make_float4(0.f, 0.f, 0.f, 0.f);
    for (int i = tid; i < BNODES; i += 256) degl[i] = 0;
    __syncthreads();

    const int b  = blockIdx.x;
    const int s0 = bstart[b];
    const int s1 = bstart[b + 1];
    const int wave = tid >> 6;
    const int lane = tid & 63;

    for (int e = s0 + wave * 4; e < s1; e += 16) {
        const int m = s1 - e;          // valid entries this quad (>=1)
        uint2 en[4];
        float v[4];
#pragma unroll
        for (int i = 0; i < 4; ++i)
            en[i] = entries[e + ((i < m) ? i : 0)];
#pragma unroll
        for (int i = 0; i < 4; ++i)
            v[i] = feat[(size_t)(en[i].x & 0x1FFFF) * D + lane];
#pragma unroll
        for (int i = 0; i < 4; ++i)
            if (i < m) {
                const int dl = (en[i].x >> 17) & (BNODES - 1);
                atomicAdd(&acc[(dl << 6) + lane], v[i] * __uint_as_float(en[i].y));
                if (lane == 0) atomicAdd(&degl[dl], 1);
            }
    }
    __syncthreads();

    const int node0 = b << BSH;
    const int r = tid >> 1;            // node within bucket
    const int h = tid & 1;             // half-row
    const int n = node0 + r;
    if (n < N_NODES) {
        const float inv = 1.0f / fmaxf((float)degl[r], 1.0f);
#pragma unroll
        for (int q = 0; q < 8; ++q) {
            float4 x = acc4[(r << 4) + h * 8 + q];
            x.x *= inv; x.y *= inv; x.z *= inv; x.w *= inv;
            agg4[(size_t)n * 16 + h * 8 + q] = x;
        }
    }
}

// ---------------------------------------------------------------------------
// K5: finalize GEMM. out[n,:] = [feat_n || agg_n] @ W2t + bias.
// 64-node tile per block; X tile + combined W in LDS.
// ---------------------------------------------------------------------------
__global__ __launch_bounds__(256) void k_final(const float4* __restrict__ feat4,
                                               const float4* __restrict__ agg4,
                                               const float* __restrict__ Wn,
                                               const float* __restrict__ Ws,
                                               const float* __restrict__ bias,
                                               float* __restrict__ out) {
    __shared__ float xt[64 * 128];   // 32 KB
    __shared__ float wt[64 * 128];   // 32 KB
    const int tid   = threadIdx.x;
    const int node0 = blockIdx.x * 64;

    for (int idx = tid; idx < 64 * 128; idx += 256) {
        int j = idx >> 7, k = idx & 127;
        wt[idx] = (k < D) ? Ws[j * D + k] : Wn[j * D + (k - D)];
    }
    float4* xt4 = (float4*)xt;
    for (int idx = tid; idx < 64 * 32; idx += 256) {
        int m = idx >> 5, q = idx & 31;
        int n = node0 + m;
        float4 v = make_float4(0.f, 0.f, 0.f, 0.f);
        if (n < N_NODES)
            v = (q < 16) ? feat4[(size_t)n * 16 + q] : agg4[(size_t)n * 16 + (q - 16)];
        xt4[m * 32 + q] = v;
    }
    __syncthreads();

    const int j  = tid & 63;   // output column
    const int mg = tid >> 6;   // wave -> node subgroup
    const float bv = bias[j];
    float acc[16];
#pragma unroll
    for (int i = 0; i < 16; ++i) acc[i] = 0.f;

    for (int k = 0; k < 128; k += 4) {
        float4 wv = *(const float4*)&wt[j * 128 + k];
#pragma unroll
        for (int i = 0; i < 16; ++i) {
            float4 xv = *(const float4*)&xt[(mg * 16 + i) * 128 + k];
            acc[i] = fmaf(wv.x, xv.x, acc[i]);
            acc[i] = fmaf(wv.y, xv.y, acc[i]);
            acc[i] = fmaf(wv.z, xv.z, acc[i]);
            acc[i] = fmaf(wv.w, xv.w, acc[i]);
        }
    }
#pragma unroll
    for (int i = 0; i < 16; ++i) {
        int n = node0 + mg * 16 + i;
        if (n < N_NODES) out[(size_t)n * D + j] = acc[i] + bv;
    }
}

// ---------------------------------------------------------------------------
// Fallback path (R1): atomic scatter + shuffle finalize, if ws is too small.
// ---------------------------------------------------------------------------
__global__ __launch_bounds__(256) void fb_zero(float4* __restrict__ out4,
                                               float* __restrict__ deg) {
    const int stride = gridDim.x * blockDim.x;
    int i = blockIdx.x * blockDim.x + threadIdx.x;
    const int total4 = (N_NODES * D) / 4;
    for (int idx = i; idx < total4; idx += stride)
        out4[idx] = make_float4(0.f, 0.f, 0.f, 0.f);
    for (int idx = i; idx < N_NODES; idx += stride)
        deg[idx] = 0.f;
}

__global__ __launch_bounds__(256) void fb_scatter(
    const float* __restrict__ feat, const int* __restrict__ src,
    const int* __restrict__ dst, const float* __restrict__ ew,
    float* __restrict__ out, float* __restrict__ deg) {
    const int gid  = blockIdx.x * blockDim.x + threadIdx.x;
    const int e    = gid >> 6;
    const int lane = gid & 63;
    if (e >= N_EDGES) return;
    atomicAdd(&out[(size_t)dst[e] * D + lane], feat[(size_t)src[e] * D + lane] * ew[e]);
    if (lane == 0) atomicAdd(&deg[dst[e]], 1.0f);
}

__global__ __launch_bounds__(256) void fb_finalize(
    const float* __restrict__ feat, const float* __restrict__ Wn,
    const float* __restrict__ Ws, const float* __restrict__ bias,
    const float* __restrict__ deg, float* __restrict__ out) {
    __shared__ float lWn[D * 65];
    __shared__ float lWs[D * 65];
    for (int idx = threadIdx.x; idx < D * D; idx += 256) {
        const int r = idx >> 6, c = idx & 63;
        lWn[r * 65 + c] = Wn[idx];
        lWs[r * 65 + c] = Ws[idx];
    }
    __syncthreads();
    const int wave = threadIdx.x >> 6;
    const int lane = threadIdx.x & 63;
    const int n = blockIdx.x * 4 + wave;
    if (n >= N_NODES) return;
    const float f  = feat[(size_t)n * D + lane];
    const float sv = out[(size_t)n * D + lane];
    const float inv = 1.0f / fmaxf(deg[n], 1.0f);
    float acc_s = 0.f, acc_n = 0.f;
#pragma unroll
    for (int k = 0; k < D; ++k) {
        acc_s += __shfl(f, k)  * lWs[lane * 65 + k];
        acc_n += __shfl(sv, k) * lWn[lane * 65 + k];
    }
    out[(size_t)n * D + lane] = acc_s + acc_n * inv + bias[lane];
}

// ---------------------------------------------------------------------------
extern "C" void kernel_launch(void* const* d_in, const int* in_sizes, int n_in,
                              void* d_out, int out_size, void* d_ws, size_t ws_size,
                              hipStream_t stream) {
    const float* feat = (const float*)d_in[0];
    const int*   src  = (const int*)  d_in[1];
    const int*   dst  = (const int*)  d_in[2];
    const float* ew   = (const float*)d_in[3];
    const float* Wn   = (const float*)d_in[4];
    const float* Ws   = (const float*)d_in[5];
    const float* bias = (const float*)d_in[6];
    float* out = (float*)d_out;
    char* ws = (char*)d_ws;

    if (ws_size >= WS_NEEDED) {
        int*   bcnt    = (int*)(ws + OFF_BCNT);
        int*   cursor  = (int*)(ws + OFF_CURSOR);
        int*   bstart  = (int*)(ws + OFF_BSTART);
        uint2* entries = (uint2*)(ws + OFF_ENTRIES);
        float* agg     = (float*)(ws + OFF_AGG);

        k_zero  <<<(NBUCK + 255) / 256, 256, 0, stream>>>(bcnt);
        k_bcount<<<NPART, 256, 0, stream>>>(dst, bcnt);
        k_scan  <<<1, 1024, 0, stream>>>(bcnt, bstart, cursor);
        k_part  <<<NPART, 256, 0, stream>>>(src, dst, ew, cursor, entries);
        k_bagg  <<<NBUCK, 256, 0, stream>>>(feat, bstart, entries, (float4*)agg);
        k_final <<<(N_NODES + 63) / 64, 256, 0, stream>>>((const float4*)feat,
                                                          (const float4*)agg,
                                                          Wn, Ws, bias, out);
    } else {
        float* deg = (float*)d_ws;
        fb_zero<<<2048, 256, 0, stream>>>((float4*)out, deg);
        fb_scatter<<<(N_EDGES * 64) / 256, 256, 0, stream>>>(feat, src, dst, ew, out, deg);
        fb_finalize<<<(N_NODES + 3) / 4, 256, 0, stream>>>(feat, Wn, Ws, bias, deg, out);
    }
}

// Round 4
// 310.702 us; speedup vs baseline: 2.9329x; 2.9329x over previous
//
#include <hip/hip_runtime.h>

// Problem constants (from reference)
constexpr int N_NODES = 100000;
constexpr int N_EDGES = 1600000;
constexpr int D = 64;          // D_IN == D_OUT == 64

// Bucketing: 128 consecutive dst nodes per bucket.
constexpr int BSH    = 7;
constexpr int BNODES = 1 << BSH;                              // 128
constexpr int NBUCK  = (N_NODES + BNODES - 1) / BNODES;       // 782
constexpr int NPART  = 200;                                   // partition blocks
constexpr int EPB    = N_EDGES / NPART;                       // 8000 edges/block (exact)
constexpr int CAP    = 4096;  // max entries/bucket in k_sort (mean 2046, sigma~45 -> 45-sigma margin)

// ---------------------------------------------------------------------------
// Workspace layout (bytes). Total <= 40,280,064 (verified available in R2/R3).
// ---------------------------------------------------------------------------
constexpr size_t OFF_BCNT    = 0;            // NBUCK ints
constexpr size_t OFF_CURSOR  = 4096;         // NBUCK ints
constexpr size_t OFF_BSTART  = 8192;         // NBUCK+1 ints
constexpr size_t OFF_STARTS  = 16384;        // N_NODES+1 ints (ends 416,388)
constexpr size_t OFF_ENTRIES = 425984;       // N_EDGES uint2 = 12.8 MB (ends 13,225,984)
constexpr size_t OFF_AGG     = 14680064;     // N_NODES*64 float = 25.6 MB
constexpr size_t WS_NEEDED   = OFF_AGG + (size_t)N_NODES * D * 4;   // 40,280,064

// ---------------------------------------------------------------------------
// K0: zero the bucket counters (ws is poisoned before every launch).
// ---------------------------------------------------------------------------
__global__ __launch_bounds__(256) void k_zero(int* __restrict__ bcnt) {
    int i = blockIdx.x * 256 + threadIdx.x;
    if (i < NBUCK) bcnt[i] = 0;
}

// ---------------------------------------------------------------------------
// K1: per-block LDS histogram of dst buckets -> global bucket counts.
// ---------------------------------------------------------------------------
__global__ __launch_bounds__(256) void k_bcount(const int* __restrict__ dst,
                                                int* __restrict__ bcnt) {
    __shared__ int l[NBUCK];
    const int tid  = threadIdx.x;
    const int base = blockIdx.x * EPB;
    for (int i = tid; i < NBUCK; i += 256) l[i] = 0;
    __syncthreads();
    for (int k = tid; k < EPB; k += 256)
        atomicAdd(&l[dst[base + k] >> BSH], 1);
    __syncthreads();
    for (int b = tid; b < NBUCK; b += 256)
        if (l[b]) atomicAdd(&bcnt[b], l[b]);
}

// ---------------------------------------------------------------------------
// K2: exclusive scan of the 782 bucket counts (one 1024-thread block).
// Writes bstart[0..NBUCK], init cursors, and starts[N_NODES] = N_EDGES.
// ---------------------------------------------------------------------------
__global__ __launch_bounds__(1024) void k_scan(const int* __restrict__ bcnt,
                                               int* __restrict__ bstart,
                                               int* __restrict__ cursor,
                                               int* __restrict__ starts) {
    __shared__ int s[1024];
    const int tid = threadIdx.x;
    const int v = (tid < NBUCK) ? bcnt[tid] : 0;
    s[tid] = v;
    __syncthreads();
    for (int off = 1; off < 1024; off <<= 1) {
        int u = (tid >= off) ? s[tid - off] : 0;
        __syncthreads();
        s[tid] += u;
        __syncthreads();
    }
    const int excl = s[tid] - v;
    if (tid <= NBUCK) bstart[tid] = excl;   // tid==NBUCK lands on N_EDGES
    if (tid < NBUCK)  cursor[tid] = excl;
    if (tid == 0)     starts[N_NODES] = N_EDGES;
}

// ---------------------------------------------------------------------------
// K3: partition edges into bucket-contiguous entries.
// Per-block LDS hist -> one atomic range reservation per (block,bucket) ->
// scatter {src | dst_local<<17, weight} in ~10-entry contiguous runs.
// ---------------------------------------------------------------------------
__global__ __launch_bounds__(256) void k_part(const int* __restrict__ src,
                                              const int* __restrict__ dst,
                                              const float* __restrict__ ew,
                                              int* __restrict__ cursor,
                                              uint2* __restrict__ entries) {
    __shared__ int l[NBUCK];
    const int tid  = threadIdx.x;
    const int base = blockIdx.x * EPB;
    for (int i = tid; i < NBUCK; i += 256) l[i] = 0;
    __syncthreads();
    for (int k = tid; k < EPB; k += 256)
        atomicAdd(&l[dst[base + k] >> BSH], 1);
    __syncthreads();
    for (int b = tid; b < NBUCK; b += 256) {
        const int c = l[b];
        l[b] = c ? atomicAdd(&cursor[b], c) : 0;
    }
    __syncthreads();
    for (int k = tid; k < EPB; k += 256) {
        const int e = base + k;
        const int d = dst[e];
        const int pos = atomicAdd(&l[d >> BSH], 1);
        entries[pos] = make_uint2((unsigned)src[e] | ((unsigned)(d & (BNODES - 1)) << 17),
                                  __float_as_uint(ew[e]));
    }
}

// ---------------------------------------------------------------------------
// K4: per-bucket counting sort by destination node (in place, staged in LDS)
// + emit per-node CSR starts. One block per bucket. Only small int LDS
// atomics (~2K lane-ops/block) — no bulk per-lane LDS float atomics (R3's
// k_bagg showed those serialize at ~4 cyc/lane).
// ---------------------------------------------------------------------------
__global__ __launch_bounds__(256) void k_sort(uint2* __restrict__ entries,
                                              const int* __restrict__ bstart,
                                              int* __restrict__ starts) {
    __shared__ uint2 ent[CAP];        // 32 KB
    __shared__ int h[BNODES];
    __shared__ int sc[BNODES];
    __shared__ int cur[BNODES];
    const int tid = threadIdx.x;
    const int b   = blockIdx.x;
    const int s0  = bstart[b];
    const int s1  = bstart[b + 1];
    const int cnt = (s1 - s0 <= CAP) ? (s1 - s0) : CAP;

    for (int i = tid; i < BNODES; i += 256) h[i] = 0;
    __syncthreads();
    for (int i = tid; i < cnt; i += 256) {
        uint2 e = entries[s0 + i];
        ent[i] = e;
        atomicAdd(&h[(e.x >> 17) & (BNODES - 1)], 1);
    }
    __syncthreads();
    if (tid < BNODES) sc[tid] = h[tid];
    __syncthreads();
    for (int off = 1; off < BNODES; off <<= 1) {
        int u = 0;
        if (tid < BNODES && tid >= off) u = sc[tid - off];
        __syncthreads();
        if (tid < BNODES) sc[tid] += u;
        __syncthreads();
    }
    if (tid < BNODES) {
        const int excl = sc[tid] - h[tid];
        cur[tid] = excl;
        const int node = (b << BSH) + tid;
        if (node < N_NODES) starts[node] = s0 + excl;
    }
    __syncthreads();
    for (int i = tid; i < cnt; i += 256) {
        uint2 e = ent[i];
        const int pos = atomicAdd(&cur[(e.x >> 17) & (BNODES - 1)], 1);
        entries[s0 + pos] = e;
    }
}

// ---------------------------------------------------------------------------
// K5: mean-aggregate incoming edges (R2-proven structure: wave per node,
// 4 groups of 16 lanes, register accumulation, no atomics).
// ---------------------------------------------------------------------------
__global__ __launch_bounds__(256) void k_agg(const float4* __restrict__ feat4,
                                             const int* __restrict__ starts,
                                             const uint2* __restrict__ entries,
                                             float4* __restrict__ agg4) {
    const int wave = threadIdx.x >> 6;
    const int lane = threadIdx.x & 63;
    const int n = blockIdx.x * 4 + wave;
    if (n >= N_NODES) return;
    const int group = lane >> 4;
    const int gl    = lane & 15;
    const int s0 = starts[n];
    const int s1 = starts[n + 1];

    float4 acc = make_float4(0.f, 0.f, 0.f, 0.f);
    for (int e = s0 + group; e < s1; e += 4) {
        uint2 en = entries[e];
        float w  = __uint_as_float(en.y);
        float4 v = feat4[(size_t)(en.x & 0x1FFFF) * 16 + gl];
        acc.x = fmaf(v.x, w, acc.x);
        acc.y = fmaf(v.y, w, acc.y);
        acc.z = fmaf(v.z, w, acc.z);
        acc.w = fmaf(v.w, w, acc.w);
    }
#pragma unroll
    for (int m = 16; m <= 32; m <<= 1) {
        acc.x += __shfl_xor(acc.x, m);
        acc.y += __shfl_xor(acc.y, m);
        acc.z += __shfl_xor(acc.z, m);
        acc.w += __shfl_xor(acc.w, m);
    }
    if (group == 0) {
        const float inv = 1.0f / fmaxf((float)(s1 - s0), 1.0f);
        acc.x *= inv; acc.y *= inv; acc.z *= inv; acc.w *= inv;
        agg4[(size_t)n * 16 + gl] = acc;
    }
}

// ---------------------------------------------------------------------------
// K6: finalize GEMM. out[n,:] = [feat_n || agg_n] @ W2t + bias.
// ---------------------------------------------------------------------------
__global__ __launch_bounds__(256) void k_final(const float4* __restrict__ feat4,
                                               const float4* __restrict__ agg4,
                                               const float* __restrict__ Wn,
                                               const float* __restrict__ Ws,
                                               const float* __restrict__ bias,
                                               float* __restrict__ out) {
    __shared__ float xt[64 * 128];   // 32 KB
    __shared__ float wt[64 * 128];   // 32 KB
    const int tid   = threadIdx.x;
    const int node0 = blockIdx.x * 64;

    for (int idx = tid; idx < 64 * 128; idx += 256) {
        int j = idx >> 7, k = idx & 127;
        wt[idx] = (k < D) ? Ws[j * D + k] : Wn[j * D + (k - D)];
    }
    float4* xt4 = (float4*)xt;
    for (int idx = tid; idx < 64 * 32; idx += 256) {
        int m = idx >> 5, q = idx & 31;
        int n = node0 + m;
        float4 v = make_float4(0.f, 0.f, 0.f, 0.f);
        if (n < N_NODES)
            v = (q < 16) ? feat4[(size_t)n * 16 + q] : agg4[(size_t)n * 16 + (q - 16)];
        xt4[m * 32 + q] = v;
    }
    __syncthreads();

    const int j  = tid & 63;   // output column
    const int mg = tid >> 6;   // wave -> node subgroup
    const float bv = bias[j];
    float acc[16];
#pragma unroll
    for (int i = 0; i < 16; ++i) acc[i] = 0.f;

    for (int k = 0; k < 128; k += 4) {
        float4 wv = *(const float4*)&wt[j * 128 + k];
#pragma unroll
        for (int i = 0; i < 16; ++i) {
            float4 xv = *(const float4*)&xt[(mg * 16 + i) * 128 + k];
            acc[i] = fmaf(wv.x, xv.x, acc[i]);
            acc[i] = fmaf(wv.y, xv.y, acc[i]);
            acc[i] = fmaf(wv.z, xv.z, acc[i]);
            acc[i] = fmaf(wv.w, xv.w, acc[i]);
        }
    }
#pragma unroll
    for (int i = 0; i < 16; ++i) {
        int n = node0 + mg * 16 + i;
        if (n < N_NODES) out[(size_t)n * D + j] = acc[i] + bv;
    }
}

// ---------------------------------------------------------------------------
// Fallback path (R1): atomic scatter + shuffle finalize, if ws is too small.
// ---------------------------------------------------------------------------
__global__ __launch_bounds__(256) void fb_zero(float4* __restrict__ out4,
                                               float* __restrict__ deg) {
    const int stride = gridDim.x * blockDim.x;
    int i = blockIdx.x * blockDim.x + threadIdx.x;
    const int total4 = (N_NODES * D) / 4;
    for (int idx = i; idx < total4; idx += stride)
        out4[idx] = make_float4(0.f, 0.f, 0.f, 0.f);
    for (int idx = i; idx < N_NODES; idx += stride)
        deg[idx] = 0.f;
}

__global__ __launch_bounds__(256) void fb_scatter(
    const float* __restrict__ feat, const int* __restrict__ src,
    const int* __restrict__ dst, const float* __restrict__ ew,
    float* __restrict__ out, float* __restrict__ deg) {
    const int gid  = blockIdx.x * blockDim.x + threadIdx.x;
    const int e    = gid >> 6;
    const int lane = gid & 63;
    if (e >= N_EDGES) return;
    atomicAdd(&out[(size_t)dst[e] * D + lane], feat[(size_t)src[e] * D + lane] * ew[e]);
    if (lane == 0) atomicAdd(&deg[dst[e]], 1.0f);
}

__global__ __launch_bounds__(256) void fb_finalize(
    const float* __restrict__ feat, const float* __restrict__ Wn,
    const float* __restrict__ Ws, const float* __restrict__ bias,
    const float* __restrict__ deg, float* __restrict__ out) {
    __shared__ float lWn[D * 65];
    __shared__ float lWs[D * 65];
    for (int idx = threadIdx.x; idx < D * D; idx += 256) {
        const int r = idx >> 6, c = idx & 63;
        lWn[r * 65 + c] = Wn[idx];
        lWs[r * 65 + c] = Ws[idx];
    }
    __syncthreads();
    const int wave = threadIdx.x >> 6;
    const int lane = threadIdx.x & 63;
    const int n = blockIdx.x * 4 + wave;
    if (n >= N_NODES) return;
    const float f  = feat[(size_t)n * D + lane];
    const float sv = out[(size_t)n * D + lane];
    const float inv = 1.0f / fmaxf(deg[n], 1.0f);
    float acc_s = 0.f, acc_n = 0.f;
#pragma unroll
    for (int k = 0; k < D; ++k) {
        acc_s += __shfl(f, k)  * lWs[lane * 65 + k];
        acc_n += __shfl(sv, k) * lWn[lane * 65 + k];
    }
    out[(size_t)n * D + lane] = acc_s + acc_n * inv + bias[lane];
}

// ---------------------------------------------------------------------------
extern "C" void kernel_launch(void* const* d_in, const int* in_sizes, int n_in,
                              void* d_out, int out_size, void* d_ws, size_t ws_size,
                              hipStream_t stream) {
    const float* feat = (const float*)d_in[0];
    const int*   src  = (const int*)  d_in[1];
    const int*   dst  = (const int*)  d_in[2];
    const float* ew   = (const float*)d_in[3];
    const float* Wn   = (const float*)d_in[4];
    const float* Ws   = (const float*)d_in[5];
    const float* bias = (const float*)d_in[6];
    float* out = (float*)d_out;
    char* ws = (char*)d_ws;

    if (ws_size >= WS_NEEDED) {
        int*   bcnt    = (int*)(ws + OFF_BCNT);
        int*   cursor  = (int*)(ws + OFF_CURSOR);
        int*   bstart  = (int*)(ws + OFF_BSTART);
        int*   starts  = (int*)(ws + OFF_STARTS);
        uint2* entries = (uint2*)(ws + OFF_ENTRIES);
        float* agg     = (float*)(ws + OFF_AGG);

        k_zero  <<<(NBUCK + 255) / 256, 256, 0, stream>>>(bcnt);
        k_bcount<<<NPART, 256, 0, stream>>>(dst, bcnt);
        k_scan  <<<1, 1024, 0, stream>>>(bcnt, bstart, cursor, starts);
        k_part  <<<NPART, 256, 0, stream>>>(src, dst, ew, cursor, entries);
        k_sort  <<<NBUCK, 256, 0, stream>>>(entries, bstart, starts);
        k_agg   <<<(N_NODES + 3) / 4, 256, 0, stream>>>((const float4*)feat, starts,
                                                        entries, (float4*)agg);
        k_final <<<(N_NODES + 63) / 64, 256, 0, stream>>>((const float4*)feat,
                                                          (const float4*)agg,
                                                          Wn, Ws, bias, out);
    } else {
        float* deg = (float*)d_ws;
        fb_zero<<<2048, 256, 0, stream>>>((float4*)out, deg);
        fb_scatter<<<(N_EDGES * 64) / 256, 256, 0, stream>>>(feat, src, dst, ew, out, deg);
        fb_finalize<<<(N_NODES + 3) / 4, 256, 0, stream>>>(feat, Wn, Ws, bias, deg, out);
    }
}

// Round 5
// 249.134 us; speedup vs baseline: 3.6577x; 1.2471x over previous
//
#include <hip/hip_runtime.h>

// Problem constants (from reference)
constexpr int N_NODES = 100000;
constexpr int N_EDGES = 1600000;
constexpr int D = 64;          // D_IN == D_OUT == 64

// Bucketing: 128 consecutive dst nodes per bucket.
constexpr int BSH    = 7;
constexpr int BNODES = 1 << BSH;                              // 128
constexpr int NBUCK  = (N_NODES + BNODES - 1) / BNODES;       // 782
constexpr int NPART  = 200;                                   // partition blocks
constexpr int EPB    = N_EDGES / NPART;                       // 8000 edges/block (exact)
constexpr int CAP    = 4096;  // max entries/bucket in k_sort (mean 2046, sigma~45)

// ---------------------------------------------------------------------------
// Workspace layout (bytes). Total == 40,280,064 (same as R2-R4, verified).
// ---------------------------------------------------------------------------
constexpr size_t OFF_BCNT    = 0;            // NBUCK ints
constexpr size_t OFF_CURSOR  = 4096;         // NBUCK ints
constexpr size_t OFF_BSTART  = 8192;         // NBUCK+1 ints
constexpr size_t OFF_STARTS  = 16384;        // N_NODES+1 ints (ends 416,388)
constexpr size_t OFF_ENTRIES = 425984;       // N_EDGES uint2 = 12.8 MB (ends 13,225,984)
constexpr size_t OFF_W16     = 13500416;     // 64*128 bf16 = 16 KB
constexpr size_t OFF_AGG16   = 14680064;     // N_NODES*64 bf16 = 12.8 MB
constexpr size_t OFF_FEAT16  = 27480064;     // N_NODES*64 bf16 = 12.8 MB (ends 40,280,064)
constexpr size_t WS_NEEDED   = OFF_FEAT16 + (size_t)N_NODES * D * 2;  // 40,280,064

typedef short  bf16x8 __attribute__((ext_vector_type(8)));
typedef float  f32x4  __attribute__((ext_vector_type(4)));

__device__ __forceinline__ unsigned short f2bf(float f) {   // RNE f32 -> bf16
    unsigned u = __float_as_uint(f);
    u += 0x7fffu + ((u >> 16) & 1u);
    return (unsigned short)(u >> 16);
}

// ---------------------------------------------------------------------------
// K-1: convert feat f32 -> bf16; block 0 also builds combined W16[j][k]
// (k<64 = W_self, k>=64 = W_neigh), matching X = [feat || agg].
// ---------------------------------------------------------------------------
__global__ __launch_bounds__(256) void k_cvt(const float4* __restrict__ feat4,
                                             unsigned short* __restrict__ feat16,
                                             const float* __restrict__ Wn,
                                             const float* __restrict__ Ws,
                                             unsigned short* __restrict__ W16) {
    const int i = blockIdx.x * 256 + threadIdx.x;   // 1.6M threads, 4 floats each
    float4 v = feat4[i];
    ushort4 o;
    o.x = f2bf(v.x); o.y = f2bf(v.y); o.z = f2bf(v.z); o.w = f2bf(v.w);
    *(ushort4*)&feat16[(size_t)i * 4] = o;
    if (blockIdx.x == 0) {
        for (int e = threadIdx.x; e < D * 128; e += 256) {
            const int j = e >> 7, k = e & 127;
            const float w = (k < D) ? Ws[j * D + k] : Wn[j * D + (k - D)];
            W16[e] = f2bf(w);
        }
    }
}

// ---------------------------------------------------------------------------
// K0: zero the bucket counters (ws is poisoned before every launch).
// ---------------------------------------------------------------------------
__global__ __launch_bounds__(256) void k_zero(int* __restrict__ bcnt) {
    int i = blockIdx.x * 256 + threadIdx.x;
    if (i < NBUCK) bcnt[i] = 0;
}

// ---------------------------------------------------------------------------
// K1: per-block LDS histogram of dst buckets -> global bucket counts.
// ---------------------------------------------------------------------------
__global__ __launch_bounds__(256) void k_bcount(const int* __restrict__ dst,
                                                int* __restrict__ bcnt) {
    __shared__ int l[NBUCK];
    const int tid  = threadIdx.x;
    const int base = blockIdx.x * EPB;
    for (int i = tid; i < NBUCK; i += 256) l[i] = 0;
    __syncthreads();
    for (int k = tid; k < EPB; k += 256)
        atomicAdd(&l[dst[base + k] >> BSH], 1);
    __syncthreads();
    for (int b = tid; b < NBUCK; b += 256)
        if (l[b]) atomicAdd(&bcnt[b], l[b]);
}

// ---------------------------------------------------------------------------
// K2: exclusive scan of the 782 bucket counts (one 1024-thread block).
// ---------------------------------------------------------------------------
__global__ __launch_bounds__(1024) void k_scan(const int* __restrict__ bcnt,
                                               int* __restrict__ bstart,
                                               int* __restrict__ cursor,
                                               int* __restrict__ starts) {
    __shared__ int s[1024];
    const int tid = threadIdx.x;
    const int v = (tid < NBUCK) ? bcnt[tid] : 0;
    s[tid] = v;
    __syncthreads();
    for (int off = 1; off < 1024; off <<= 1) {
        int u = (tid >= off) ? s[tid - off] : 0;
        __syncthreads();
        s[tid] += u;
        __syncthreads();
    }
    const int excl = s[tid] - v;
    if (tid <= NBUCK) bstart[tid] = excl;   // tid==NBUCK lands on N_EDGES
    if (tid < NBUCK)  cursor[tid] = excl;
    if (tid == 0)     starts[N_NODES] = N_EDGES;
}

// ---------------------------------------------------------------------------
// K3: partition edges into bucket-contiguous entries.
// ---------------------------------------------------------------------------
__global__ __launch_bounds__(256) void k_part(const int* __restrict__ src,
                                              const int* __restrict__ dst,
                                              const float* __restrict__ ew,
                                              int* __restrict__ cursor,
                                              uint2* __restrict__ entries) {
    __shared__ int l[NBUCK];
    const int tid  = threadIdx.x;
    const int base = blockIdx.x * EPB;
    for (int i = tid; i < NBUCK; i += 256) l[i] = 0;
    __syncthreads();
    for (int k = tid; k < EPB; k += 256)
        atomicAdd(&l[dst[base + k] >> BSH], 1);
    __syncthreads();
    for (int b = tid; b < NBUCK; b += 256) {
        const int c = l[b];
        l[b] = c ? atomicAdd(&cursor[b], c) : 0;
    }
    __syncthreads();
    for (int k = tid; k < EPB; k += 256) {
        const int e = base + k;
        const int d = dst[e];
        const int pos = atomicAdd(&l[d >> BSH], 1);
        entries[pos] = make_uint2((unsigned)src[e] | ((unsigned)(d & (BNODES - 1)) << 17),
                                  __float_as_uint(ew[e]));
    }
}

// ---------------------------------------------------------------------------
// K4: per-bucket counting sort by destination node + emit per-node CSR starts.
// Only small int LDS atomics (bulk per-lane LDS float atomics serialize, R3).
// ---------------------------------------------------------------------------
__global__ __launch_bounds__(256) void k_sort(uint2* __restrict__ entries,
                                              const int* __restrict__ bstart,
                                              int* __restrict__ starts) {
    __shared__ uint2 ent[CAP];        // 32 KB
    __shared__ int h[BNODES];
    __shared__ int sc[BNODES];
    __shared__ int cur[BNODES];
    const int tid = threadIdx.x;
    const int b   = blockIdx.x;
    const int s0  = bstart[b];
    const int s1  = bstart[b + 1];
    const int cnt = (s1 - s0 <= CAP) ? (s1 - s0) : CAP;

    for (int i = tid; i < BNODES; i += 256) h[i] = 0;
    __syncthreads();
    for (int i = tid; i < cnt; i += 256) {
        uint2 e = entries[s0 + i];
        ent[i] = e;
        atomicAdd(&h[(e.x >> 17) & (BNODES - 1)], 1);
    }
    __syncthreads();
    if (tid < BNODES) sc[tid] = h[tid];
    __syncthreads();
    for (int off = 1; off < BNODES; off <<= 1) {
        int u = 0;
        if (tid < BNODES && tid >= off) u = sc[tid - off];
        __syncthreads();
        if (tid < BNODES) sc[tid] += u;
        __syncthreads();
    }
    if (tid < BNODES) {
        const int excl = sc[tid] - h[tid];
        cur[tid] = excl;
        const int node = (b << BSH) + tid;
        if (node < N_NODES) starts[node] = s0 + excl;
    }
    __syncthreads();
    for (int i = tid; i < cnt; i += 256) {
        uint2 e = ent[i];
        const int pos = atomicAdd(&cur[(e.x >> 17) & (BNODES - 1)], 1);
        entries[s0 + pos] = e;
    }
}

// ---------------------------------------------------------------------------
// K5: mean-aggregate incoming edges from bf16 feat (128B/row gather, half the
// bytes of f32). Wave per node, 4 groups of 16 lanes, register accumulation,
// f32 math, bf16 output (what the MFMA finalize consumes).
// ---------------------------------------------------------------------------
__global__ __launch_bounds__(256) void k_agg(const uint2* __restrict__ feat16u2,
                                             const int* __restrict__ starts,
                                             const uint2* __restrict__ entries,
                                             uint2* __restrict__ agg16u2) {
    const int wave = threadIdx.x >> 6;
    const int lane = threadIdx.x & 63;
    const int n = blockIdx.x * 4 + wave;
    if (n >= N_NODES) return;
    const int group = lane >> 4;
    const int gl    = lane & 15;
    const int s0 = starts[n];
    const int s1 = starts[n + 1];

    float4 acc = make_float4(0.f, 0.f, 0.f, 0.f);
    for (int e = s0 + group; e < s1; e += 4) {
        const uint2 en = entries[e];
        const float w  = __uint_as_float(en.y);
        const uint2 p  = feat16u2[(size_t)(en.x & 0x1FFFF) * 16 + gl];
        acc.x = fmaf(__uint_as_float(p.x << 16),          w, acc.x);
        acc.y = fmaf(__uint_as_float(p.x & 0xFFFF0000u),  w, acc.y);
        acc.z = fmaf(__uint_as_float(p.y << 16),          w, acc.z);
        acc.w = fmaf(__uint_as_float(p.y & 0xFFFF0000u),  w, acc.w);
    }
#pragma unroll
    for (int m = 16; m <= 32; m <<= 1) {
        acc.x += __shfl_xor(acc.x, m);
        acc.y += __shfl_xor(acc.y, m);
        acc.z += __shfl_xor(acc.z, m);
        acc.w += __shfl_xor(acc.w, m);
    }
    if (group == 0) {
        const float inv = 1.0f / fmaxf((float)(s1 - s0), 1.0f);
        uint2 o;
        o.x = (unsigned)f2bf(acc.x * inv) | ((unsigned)f2bf(acc.y * inv) << 16);
        o.y = (unsigned)f2bf(acc.z * inv) | ((unsigned)f2bf(acc.w * inv) << 16);
        agg16u2[(size_t)n * 16 + gl] = o;
    }
}

// ---------------------------------------------------------------------------
// K6: finalize via bf16 MFMA, zero LDS. OUT[M=100K, N=64] = X[M,128] @ W16^T.
// Wave handles 16 nodes; A-frag A[m=lane&15][k=quad*8+j] and B-frag
// B[k=quad*8+j][n=lane&15] are contiguous 16B row-major loads from global.
// C/D: col=lane&15, row=quad*4+reg (verified gfx950 layouts).
// ---------------------------------------------------------------------------
__global__ __launch_bounds__(256) void k_final(const unsigned short* __restrict__ feat16,
                                               const unsigned short* __restrict__ agg16,
                                               const unsigned short* __restrict__ W16,
                                               const float* __restrict__ bias,
                                               float* __restrict__ out) {
    const int tid  = threadIdx.x;
    const int wave = tid >> 6, lane = tid & 63;
    const int quad = lane >> 4, r = lane & 15;
    const int node0 = blockIdx.x * 64 + wave * 16;
    int arow = node0 + r;
    if (arow > N_NODES - 1) arow = N_NODES - 1;

    bf16x8 a[4], b[4][4];
    a[0] = *(const bf16x8*)&feat16[(size_t)arow * 64 +      quad * 8];
    a[1] = *(const bf16x8*)&feat16[(size_t)arow * 64 + 32 + quad * 8];
    a[2] = *(const bf16x8*)&agg16 [(size_t)arow * 64 +      quad * 8];
    a[3] = *(const bf16x8*)&agg16 [(size_t)arow * 64 + 32 + quad * 8];
#pragma unroll
    for (int nt = 0; nt < 4; ++nt)
#pragma unroll
        for (int kc = 0; kc < 4; ++kc)
            b[nt][kc] = *(const bf16x8*)&W16[(size_t)(nt * 16 + r) * 128 + kc * 32 + quad * 8];

    f32x4 acc[4] = {};
#pragma unroll
    for (int kc = 0; kc < 4; ++kc)
#pragma unroll
        for (int nt = 0; nt < 4; ++nt)
            acc[nt] = __builtin_amdgcn_mfma_f32_16x16x32_bf16(a[kc], b[nt][kc], acc[nt], 0, 0, 0);

#pragma unroll
    for (int nt = 0; nt < 4; ++nt) {
        const float bv = bias[nt * 16 + r];
#pragma unroll
        for (int reg = 0; reg < 4; ++reg) {
            const int m = node0 + quad * 4 + reg;
            if (m < N_NODES) out[(size_t)m * 64 + nt * 16 + r] = acc[nt][reg] + bv;
        }
    }
}

// ---------------------------------------------------------------------------
// Fallback path (R1): atomic scatter + shuffle finalize, if ws is too small.
// ---------------------------------------------------------------------------
__global__ __launch_bounds__(256) void fb_zero(float4* __restrict__ out4,
                                               float* __restrict__ deg) {
    const int stride = gridDim.x * blockDim.x;
    int i = blockIdx.x * blockDim.x + threadIdx.x;
    const int total4 = (N_NODES * D) / 4;
    for (int idx = i; idx < total4; idx += stride)
        out4[idx] = make_float4(0.f, 0.f, 0.f, 0.f);
    for (int idx = i; idx < N_NODES; idx += stride)
        deg[idx] = 0.f;
}

__global__ __launch_bounds__(256) void fb_scatter(
    const float* __restrict__ feat, const int* __restrict__ src,
    const int* __restrict__ dst, const float* __restrict__ ew,
    float* __restrict__ out, float* __restrict__ deg) {
    const int gid  = blockIdx.x * blockDim.x + threadIdx.x;
    const int e    = gid >> 6;
    const int lane = gid & 63;
    if (e >= N_EDGES) return;
    atomicAdd(&out[(size_t)dst[e] * D + lane], feat[(size_t)src[e] * D + lane] * ew[e]);
    if (lane == 0) atomicAdd(&deg[dst[e]], 1.0f);
}

__global__ __launch_bounds__(256) void fb_finalize(
    const float* __restrict__ feat, const float* __restrict__ Wn,
    const float* __restrict__ Ws, const float* __restrict__ bias,
    const float* __restrict__ deg, float* __restrict__ out) {
    __shared__ float lWn[D * 65];
    __shared__ float lWs[D * 65];
    for (int idx = threadIdx.x; idx < D * D; idx += 256) {
        const int r = idx >> 6, c = idx & 63;
        lWn[r * 65 + c] = Wn[idx];
        lWs[r * 65 + c] = Ws[idx];
    }
    __syncthreads();
    const int wave = threadIdx.x >> 6;
    const int lane = threadIdx.x & 63;
    const int n = blockIdx.x * 4 + wave;
    if (n >= N_NODES) return;
    const float f  = feat[(size_t)n * D + lane];
    const float sv = out[(size_t)n * D + lane];
    const float inv = 1.0f / fmaxf(deg[n], 1.0f);
    float acc_s = 0.f, acc_n = 0.f;
#pragma unroll
    for (int k = 0; k < D; ++k) {
        acc_s += __shfl(f, k)  * lWs[lane * 65 + k];
        acc_n += __shfl(sv, k) * lWn[lane * 65 + k];
    }
    out[(size_t)n * D + lane] = acc_s + acc_n * inv + bias[lane];
}

// ---------------------------------------------------------------------------
extern "C" void kernel_launch(void* const* d_in, const int* in_sizes, int n_in,
                              void* d_out, int out_size, void* d_ws, size_t ws_size,
                              hipStream_t stream) {
    const float* feat = (const float*)d_in[0];
    const int*   src  = (const int*)  d_in[1];
    const int*   dst  = (const int*)  d_in[2];
    const float* ew   = (const float*)d_in[3];
    const float* Wn   = (const float*)d_in[4];
    const float* Ws   = (const float*)d_in[5];
    const float* bias = (const float*)d_in[6];
    float* out = (float*)d_out;
    char* ws = (char*)d_ws;

    if (ws_size >= WS_NEEDED) {
        int*   bcnt    = (int*)(ws + OFF_BCNT);
        int*   cursor  = (int*)(ws + OFF_CURSOR);
        int*   bstart  = (int*)(ws + OFF_BSTART);
        int*   starts  = (int*)(ws + OFF_STARTS);
        uint2* entries = (uint2*)(ws + OFF_ENTRIES);
        unsigned short* W16    = (unsigned short*)(ws + OFF_W16);
        unsigned short* agg16  = (unsigned short*)(ws + OFF_AGG16);
        unsigned short* feat16 = (unsigned short*)(ws + OFF_FEAT16);

        k_cvt   <<<(N_NODES * D / 4 + 255) / 256, 256, 0, stream>>>(
                    (const float4*)feat, feat16, Wn, Ws, W16);
        k_zero  <<<(NBUCK + 255) / 256, 256, 0, stream>>>(bcnt);
        k_bcount<<<NPART, 256, 0, stream>>>(dst, bcnt);
        k_scan  <<<1, 1024, 0, stream>>>(bcnt, bstart, cursor, starts);
        k_part  <<<NPART, 256, 0, stream>>>(src, dst, ew, cursor, entries);
        k_sort  <<<NBUCK, 256, 0, stream>>>(entries, bstart, starts);
        k_agg   <<<(N_NODES + 3) / 4, 256, 0, stream>>>((const uint2*)feat16, starts,
                                                        entries, (uint2*)agg16);
        k_final <<<(N_NODES + 63) / 64, 256, 0, stream>>>(feat16, agg16, W16, bias, out);
    } else {
        float* deg = (float*)d_ws;
        fb_zero<<<2048, 256, 0, stream>>>((float4*)out, deg);
        fb_scatter<<<(N_EDGES * 64) / 256, 256, 0, stream>>>(feat, src, dst, ew, out, deg);
        fb_finalize<<<(N_NODES + 3) / 4, 256, 0, stream>>>(feat, Wn, Ws, bias, deg, out);
    }
}

// Round 7
// 234.342 us; speedup vs baseline: 3.8885x; 1.0631x over previous
//
#include <hip/hip_runtime.h>

// Problem constants (from reference)
constexpr int N_NODES = 100000;
constexpr int N_EDGES = 1600000;
constexpr int D = 64;          // D_IN == D_OUT == 64

// Bucketing: 64 consecutive dst nodes per bucket (one k_bucket block each).
constexpr int BSH    = 6;
constexpr int BN     = 1 << BSH;                              // 64
constexpr int NBUCK  = (N_NODES + BN - 1) / BN;               // 1563
constexpr int NPART  = 200;                                   // partition blocks
constexpr int EPB    = N_EDGES / NPART;                       // 8000 (exact)
constexpr int CAP    = 2048;  // max entries/bucket (mean 1024, sd 32 -> 32-sigma)
constexpr int NCVT   = (N_NODES * D / 4) / 256;               // 6250 cvt blocks

// ---------------------------------------------------------------------------
// Workspace layout (bytes). Total 25,645,056 <= 40,280,064 (verified avail).
// ---------------------------------------------------------------------------
constexpr size_t OFF_BCNT    = 0;                             // NBUCK ints
constexpr size_t OFF_CURSOR  = 8192;                          // NBUCK ints
constexpr size_t OFF_BSTART  = 16384;                         // NBUCK+1 ints
constexpr size_t OFF_ENTRIES = 24576;                         // N_EDGES uint2
constexpr size_t OFF_W16     = 24576 + (size_t)N_EDGES * 8;   // 12,824,576 (16 KB)
constexpr size_t OFF_FEAT16  = 12845056;                      // N_NODES*64 bf16
constexpr size_t WS_NEEDED   = OFF_FEAT16 + (size_t)N_NODES * D * 2;  // 25,645,056

typedef short  bf16x8 __attribute__((ext_vector_type(8)));
typedef float  f32x4  __attribute__((ext_vector_type(4)));

union FragU { unsigned u[4]; bf16x8 v; };

__device__ __forceinline__ unsigned short f2bf(float f) {   // RNE f32 -> bf16
    unsigned u = __float_as_uint(f);
    u += 0x7fffu + ((u >> 16) & 1u);
    return (unsigned short)(u >> 16);
}

// ---------------------------------------------------------------------------
// K0: zero the bucket counters (ws is poisoned before every launch).
// ---------------------------------------------------------------------------
__global__ __launch_bounds__(256) void k_zero(int* __restrict__ bcnt) {
    int i = blockIdx.x * 256 + threadIdx.x;
    if (i < NBUCK) bcnt[i] = 0;
}

// ---------------------------------------------------------------------------
// K1 (fused, dispatch-level only — numerics identical to R5's k_cvt/k_bcount):
// blocks [0,NCVT) convert feat f32->bf16; [NCVT,NCVT+NPART) histogram dst
// buckets; last block builds combined W16[j][k] (k<64=W_self, k>=64=W_neigh).
// ---------------------------------------------------------------------------
__global__ __launch_bounds__(256) void k_pre(const float4* __restrict__ feat4,
                                             unsigned short* __restrict__ feat16,
                                             const float* __restrict__ Wn,
                                             const float* __restrict__ Ws,
                                             unsigned short* __restrict__ W16,
                                             const int* __restrict__ dst,
                                             int* __restrict__ bcnt) {
    __shared__ int l[NBUCK];
    const int b   = blockIdx.x;
    const int tid = threadIdx.x;
    if (b < NCVT) {
        const int i = b * 256 + tid;
        float4 v = feat4[i];
        ushort4 o;
        o.x = f2bf(v.x); o.y = f2bf(v.y); o.z = f2bf(v.z); o.w = f2bf(v.w);
        *(ushort4*)&feat16[(size_t)i * 4] = o;
    } else if (b < NCVT + NPART) {
        const int base = (b - NCVT) * EPB;
        for (int i = tid; i < NBUCK; i += 256) l[i] = 0;
        __syncthreads();
        for (int k = tid; k < EPB; k += 256)
            atomicAdd(&l[dst[base + k] >> BSH], 1);
        __syncthreads();
        for (int i = tid; i < NBUCK; i += 256)
            if (l[i]) atomicAdd(&bcnt[i], l[i]);
    } else {
        for (int e = tid; e < D * 128; e += 256) {
            const int j = e >> 7, k = e & 127;
            const float w = (k < D) ? Ws[j * D + k] : Wn[j * D + (k - D)];
            W16[e] = f2bf(w);
        }
    }
}

// ---------------------------------------------------------------------------
// K2: exclusive scan of 1563 bucket counts (one 1024-thread block, 2/thread).
// ---------------------------------------------------------------------------
__global__ __launch_bounds__(1024) void k_scan(const int* __restrict__ bcnt,
                                               int* __restrict__ bstart,
                                               int* __restrict__ cursor) {
    __shared__ int s[1024];
    const int t  = threadIdx.x;
    const int i0 = 2 * t, i1 = 2 * t + 1;
    const int c0 = (i0 < NBUCK) ? bcnt[i0] : 0;
    const int c1 = (i1 < NBUCK) ? bcnt[i1] : 0;
    const int v  = c0 + c1;
    s[t] = v;
    __syncthreads();
    for (int off = 1; off < 1024; off <<= 1) {
        int u = (t >= off) ? s[t - off] : 0;
        __syncthreads();
        s[t] += u;
        __syncthreads();
    }
    const int excl = s[t] - v;
    if (i0 < NBUCK) { bstart[i0] = excl;      cursor[i0] = excl; }
    if (i1 < NBUCK) { bstart[i1] = excl + c0; cursor[i1] = excl + c0; }
    if (t == 0) bstart[NBUCK] = N_EDGES;
}

// ---------------------------------------------------------------------------
// K3: partition edges into bucket-contiguous entries (R5-verified pattern).
// ---------------------------------------------------------------------------
__global__ __launch_bounds__(256) void k_part(const int* __restrict__ src,
                                              const int* __restrict__ dst,
                                              const float* __restrict__ ew,
                                              int* __restrict__ cursor,
                                              uint2* __restrict__ entries) {
    __shared__ int l[NBUCK];
    const int tid  = threadIdx.x;
    const int base = blockIdx.x * EPB;
    for (int i = tid; i < NBUCK; i += 256) l[i] = 0;
    __syncthreads();
    for (int k = tid; k < EPB; k += 256)
        atomicAdd(&l[dst[base + k] >> BSH], 1);
    __syncthreads();
    for (int b = tid; b < NBUCK; b += 256) {
        const int c = l[b];
        l[b] = c ? atomicAdd(&cursor[b], c) : 0;
    }
    __syncthreads();
    for (int k = tid; k < EPB; k += 256) {
        const int e = base + k;
        const int d = dst[e];
        const int pos = atomicAdd(&l[d >> BSH], 1);
        entries[pos] = make_uint2((unsigned)src[e] | ((unsigned)(d & (BN - 1)) << 17),
                                  __float_as_uint(ew[e]));
    }
}

// ---------------------------------------------------------------------------
// K4 (fused sort + aggregate + MFMA finalize), rebuilt from VERIFIED patterns
// only (vs R6, which failed accuracy):
//  - no register staging: placement re-reads entries from global (L2-warm)
//  - aggregation is R5's exact single-accumulator stride-4 loop
//  - no 16-B LDS vector loads: agg MFMA fragments assembled from uint2 loads
// ---------------------------------------------------------------------------
__global__ __launch_bounds__(256) void k_bucket(const uint2* __restrict__ feat16u2,
                                                const unsigned short* __restrict__ feat16,
                                                const int* __restrict__ bstart,
                                                const uint2* __restrict__ entries,
                                                const unsigned short* __restrict__ W16,
                                                const float* __restrict__ bias,
                                                float* __restrict__ out) {
    __shared__ uint2 ent[CAP];                        // 16 KB, bucket-relative sorted
    __shared__ __align__(16) uint2 aggrow[BN * 16];   // 8 KB (64 rows x 128 B bf16)
    __shared__ int hh[BN], st[BN], cur[BN];
    const int tid = threadIdx.x;
    const int b   = blockIdx.x;
    const int s0  = bstart[b];
    int cnt = bstart[b + 1] - s0;
    if (cnt > CAP) cnt = CAP;

    // P1: histogram (global read #1)
    if (tid < BN) hh[tid] = 0;
    __syncthreads();
    for (int i = tid; i < cnt; i += 256)
        atomicAdd(&hh[(entries[s0 + i].x >> 17) & (BN - 1)], 1);
    __syncthreads();
    // P2: scan 64 counters -> per-node starts (bucket-relative)
    if (tid < BN) st[tid] = hh[tid];
    __syncthreads();
    for (int off = 1; off < BN; off <<= 1) {
        int u = 0;
        if (tid < BN && tid >= off) u = st[tid - off];
        __syncthreads();
        if (tid < BN) st[tid] += u;
        __syncthreads();
    }
    if (tid < BN) { const int e0 = st[tid] - hh[tid]; st[tid] = e0; cur[tid] = e0; }
    __syncthreads();
    // P3: place sorted into LDS (global read #2, L2-warm)
    for (int i = tid; i < cnt; i += 256) {
        uint2 e = entries[s0 + i];
        const int pos = atomicAdd(&cur[(e.x >> 17) & (BN - 1)], 1);
        ent[pos] = e;
    }
    __syncthreads();

    // P4: aggregate — R5 k_agg structure (single acc, 4 groups, stride 4)
    const int wave = tid >> 6, lane = tid & 63;
    const int group = lane >> 4, gl = lane & 15;
    for (int t = 0; t < 16; ++t) {
        const int dl  = wave * 16 + t;
        const int ss  = st[dl];
        const int deg = hh[dl];
        const int se  = ss + deg;
        float4 acc = make_float4(0.f, 0.f, 0.f, 0.f);
        for (int e = ss + group; e < se; e += 4) {
            const uint2 en = ent[e];
            const float w  = __uint_as_float(en.y);
            const uint2 p  = feat16u2[(size_t)(en.x & 0x1FFFF) * 16 + gl];
            acc.x = fmaf(__uint_as_float(p.x << 16),         w, acc.x);
            acc.y = fmaf(__uint_as_float(p.x & 0xFFFF0000u), w, acc.y);
            acc.z = fmaf(__uint_as_float(p.y << 16),         w, acc.z);
            acc.w = fmaf(__uint_as_float(p.y & 0xFFFF0000u), w, acc.w);
        }
#pragma unroll
        for (int m = 16; m <= 32; m <<= 1) {
            acc.x += __shfl_xor(acc.x, m);
            acc.y += __shfl_xor(acc.y, m);
            acc.z += __shfl_xor(acc.z, m);
            acc.w += __shfl_xor(acc.w, m);
        }
        if (group == 0) {
            const float inv = 1.0f / fmaxf((float)deg, 1.0f);
            uint2 o;
            o.x = (unsigned)f2bf(acc.x * inv) | ((unsigned)f2bf(acc.y * inv) << 16);
            o.y = (unsigned)f2bf(acc.z * inv) | ((unsigned)f2bf(acc.w * inv) << 16);
            aggrow[dl * 16 + gl] = o;
        }
    }
    __syncthreads();

    // P5: MFMA finalize (R5-verified layouts). agg frags via uint2 LDS loads.
    const int quad = lane >> 4, r = lane & 15;
    const int node0 = b * BN + wave * 16;
    int arow = node0 + r;
    if (arow > N_NODES - 1) arow = N_NODES - 1;

    bf16x8 a[4], bb[4][4];
    a[0] = *(const bf16x8*)&feat16[(size_t)arow * 64 +      quad * 8];
    a[1] = *(const bf16x8*)&feat16[(size_t)arow * 64 + 32 + quad * 8];
    {
        const int rbase = (wave * 16 + r) * 16;
        FragU f2, f3;
        uint2 lo = aggrow[rbase + 2 * quad];
        uint2 hi = aggrow[rbase + 2 * quad + 1];
        f2.u[0] = lo.x; f2.u[1] = lo.y; f2.u[2] = hi.x; f2.u[3] = hi.y;
        lo = aggrow[rbase + 8 + 2 * quad];
        hi = aggrow[rbase + 8 + 2 * quad + 1];
        f3.u[0] = lo.x; f3.u[1] = lo.y; f3.u[2] = hi.x; f3.u[3] = hi.y;
        a[2] = f2.v;
        a[3] = f3.v;
    }
#pragma unroll
    for (int nt = 0; nt < 4; ++nt)
#pragma unroll
        for (int kc = 0; kc < 4; ++kc)
            bb[nt][kc] = *(const bf16x8*)&W16[(size_t)(nt * 16 + r) * 128 + kc * 32 + quad * 8];

    f32x4 acc[4] = {};
#pragma unroll
    for (int kc = 0; kc < 4; ++kc)
#pragma unroll
        for (int nt = 0; nt < 4; ++nt)
            acc[nt] = __builtin_amdgcn_mfma_f32_16x16x32_bf16(a[kc], bb[nt][kc], acc[nt], 0, 0, 0);

#pragma unroll
    for (int nt = 0; nt < 4; ++nt) {
        const float bv = bias[nt * 16 + r];
#pragma unroll
        for (int reg = 0; reg < 4; ++reg) {
            const int m = node0 + quad * 4 + reg;
            if (m < N_NODES) out[(size_t)m * 64 + nt * 16 + r] = acc[nt][reg] + bv;
        }
    }
}

// ---------------------------------------------------------------------------
// Fallback path (R1): atomic scatter + shuffle finalize, if ws is too small.
// ---------------------------------------------------------------------------
__global__ __launch_bounds__(256) void fb_zero(float4* __restrict__ out4,
                                               float* __restrict__ deg) {
    const int stride = gridDim.x * blockDim.x;
    int i = blockIdx.x * blockDim.x + threadIdx.x;
    const int total4 = (N_NODES * D) / 4;
    for (int idx = i; idx < total4; idx += stride)
        out4[idx] = make_float4(0.f, 0.f, 0.f, 0.f);
    for (int idx = i; idx < N_NODES; idx += stride)
        deg[idx] = 0.f;
}

__global__ __launch_bounds__(256) void fb_scatter(
    const float* __restrict__ feat, const int* __restrict__ src,
    const int* __restrict__ dst, const float* __restrict__ ew,
    float* __restrict__ out, float* __restrict__ deg) {
    const int gid  = blockIdx.x * blockDim.x + threadIdx.x;
    const int e    = gid >> 6;
    const int lane = gid & 63;
    if (e >= N_EDGES) return;
    atomicAdd(&out[(size_t)dst[e] * D + lane], feat[(size_t)src[e] * D + lane] * ew[e]);
    if (lane == 0) atomicAdd(&deg[dst[e]], 1.0f);
}

__global__ __launch_bounds__(256) void fb_finalize(
    const float* __restrict__ feat, const float* __restrict__ Wn,
    const float* __restrict__ Ws, const float* __restrict__ bias,
    const float* __restrict__ deg, float* __restrict__ out) {
    __shared__ float lWn[D * 65];
    __shared__ float lWs[D * 65];
    for (int idx = threadIdx.x; idx < D * D; idx += 256) {
        const int r = idx >> 6, c = idx & 63;
        lWn[r * 65 + c] = Wn[idx];
        lWs[r * 65 + c] = Ws[idx];
    }
    __syncthreads();
    const int wave = threadIdx.x >> 6;
    const int lane = threadIdx.x & 63;
    const int n = blockIdx.x * 4 + wave;
    if (n >= N_NODES) return;
    const float f  = feat[(size_t)n * D + lane];
    const float sv = out[(size_t)n * D + lane];
    const float inv = 1.0f / fmaxf(deg[n], 1.0f);
    float acc_s = 0.f, acc_n = 0.f;
#pragma unroll
    for (int k = 0; k < D; ++k) {
        acc_s += __shfl(f, k)  * lWs[lane * 65 + k];
        acc_n += __shfl(sv, k) * lWn[lane * 65 + k];
    }
    out[(size_t)n * D + lane] = acc_s + acc_n * inv + bias[lane];
}

// ---------------------------------------------------------------------------
extern "C" void kernel_launch(void* const* d_in, const int* in_sizes, int n_in,
                              void* d_out, int out_size, void* d_ws, size_t ws_size,
                              hipStream_t stream) {
    const float* feat = (const float*)d_in[0];
    const int*   src  = (const int*)  d_in[1];
    const int*   dst  = (const int*)  d_in[2];
    const float* ew   = (const float*)d_in[3];
    const float* Wn   = (const float*)d_in[4];
    const float* Ws   = (const float*)d_in[5];
    const float* bias = (const float*)d_in[6];
    float* out = (float*)d_out;
    char* ws = (char*)d_ws;

    if (ws_size >= WS_NEEDED) {
        int*   bcnt    = (int*)(ws + OFF_BCNT);
        int*   cursor  = (int*)(ws + OFF_CURSOR);
        int*   bstart  = (int*)(ws + OFF_BSTART);
        uint2* entries = (uint2*)(ws + OFF_ENTRIES);
        unsigned short* W16    = (unsigned short*)(ws + OFF_W16);
        unsigned short* feat16 = (unsigned short*)(ws + OFF_FEAT16);

        k_zero  <<<(NBUCK + 255) / 256, 256, 0, stream>>>(bcnt);
        k_pre   <<<NCVT + NPART + 1, 256, 0, stream>>>((const float4*)feat, feat16,
                                                       Wn, Ws, W16, dst, bcnt);
        k_scan  <<<1, 1024, 0, stream>>>(bcnt, bstart, cursor);
        k_part  <<<NPART, 256, 0, stream>>>(src, dst, ew, cursor, entries);
        k_bucket<<<NBUCK, 256, 0, stream>>>((const uint2*)feat16, feat16, bstart,
                                            entries, W16, bias, out);
    } else {
        float* deg = (float*)d_ws;
        fb_zero<<<2048, 256, 0, stream>>>((float4*)out, deg);
        fb_scatter<<<(N_EDGES * 64) / 256, 256, 0, stream>>>(feat, src, dst, ew, out, deg);
        fb_finalize<<<(N_NODES + 3) / 4, 256, 0, stream>>>(feat, Wn, Ws, bias, deg, out);
    }
}